// Round 10
// baseline (394.213 us; speedup 1.0000x reference)
//
#include <hip/hip_runtime.h>
#include <math.h>

namespace {

constexpr int B = 4;
constexpr int C = 512;
constexpr int NH = 32;          // heads
constexpr int CPH = 16;         // channels per head
constexpr int N = 32 * 32 * 32; // 32768 spatial
constexpr int JG = 8;           // blocks per head
constexpr int CPB = 4;          // chunks (1024 n) per block
constexpr int NJ = 32;          // chunks per head (fallback path)
constexpr int NREC = NJ * 4;    // fallback wave-records per head
constexpr long YSIZE = (long)B * C * N;  // 67,108,864

typedef float f4v __attribute__((ext_vector_type(4)));

__device__ inline float wrs(float v) {
#pragma unroll
  for (int o = 32; o > 0; o >>= 1) v += __shfl_xor(v, o);
  return v;
}

// DPP add, compile-time control + row mask (disabled rows: old=0 added).
template <int CTRL, int RM = 0xF>
__device__ __forceinline__ float dppAdd(float v) {
  const int r = __builtin_amdgcn_update_dpp(
      0, __float_as_int(v), CTRL, RM, 0xF, true);
  return v + __int_as_float(r);
}
// Full 64-lane sum on the VALU pipe only; total valid in row 3 (lanes 48-63).
__device__ __forceinline__ float waveSumRow3(float v) {
  v = dppAdd<0xB1>(v);          // + lane^1
  v = dppAdd<0x4E>(v);          // + lane^2
  v = dppAdd<0x124>(v);         // row_ror:4
  v = dppAdd<0x128>(v);         // row_ror:8 -> 16-lane row sum
  v = dppAdd<0x142, 0xA>(v);    // row_bcast15: rows 1,3 += rows 0,2
  v = dppAdd<0x143, 0xC>(v);    // row_bcast31: rows 2,3 += lower half
  return v;
}

// ---------------------------------------------------------------------------
// FUSED cooperative kernel. grid (JG=8, NH, B) = 1024 blocks (co-resident at
// 4 blocks/CU), 256 threads. Phase 1: block accumulates its 4 chunks' softmax
// partials (pure-DPP wave sums, 1 record/wave). Release-store records, bump
// head counter. Spin (relaxed agent loads) until all 8 blocks of the head
// arrive. Finalize head-locally (grouped MLP is head-local!). Phase 2:
// re-read the SAME just-streamed x chunks (reverse order, L2/L3-fresh,
// ~64 MB active working set) and write y with NT stores. dp via atomicAdd.
__global__ __launch_bounds__(256, 4) void fused(
    const float* __restrict__ x, const float* __restrict__ kw,
    const float* __restrict__ qw, const float* __restrict__ pw1,
    const float* __restrict__ pb1, const float* __restrict__ pw2,
    const float* __restrict__ pb2, float* __restrict__ prec,
    int* __restrict__ cnt, float* __restrict__ dp, float* __restrict__ y) {
  const int jg = blockIdx.x, h = blockIdx.y, b = blockIdx.z;
  const int t = threadIdx.x, lane = t & 63, wid = t >> 6, p = lane & 15;
  const int head = b * NH + h;
  const float* xh = x + ((long)(b * C + h * CPH)) * N;

  // ---- phase 1: softmax partials over this block's 4 chunks ----
  float o0 = 0.f, o1 = 0.f, o2 = 0.f, o3 = 0.f;
  for (int s = 0; s < CPB; ++s) {
    const float* xs = xh + (long)(jg * CPB + s) * 1024 + t * 4;
    float4 xv[CPH];
#pragma unroll
    for (int c = 0; c < CPH; ++c) xv[c] = *(const float4*)(xs + (long)c * N);
    float4 lk = make_float4(0.f, 0.f, 0.f, 0.f);
    float4 lq = make_float4(0.f, 0.f, 0.f, 0.f);
#pragma unroll
    for (int c = 0; c < CPH; ++c) {
      const float wk = kw[h * CPH + c], wq = qw[h * CPH + c];  // uniform->SGPR
      lk.x += xv[c].x * wk; lk.y += xv[c].y * wk;
      lk.z += xv[c].z * wk; lk.w += xv[c].w * wk;
      lq.x += xv[c].x * wq; lq.y += xv[c].y * wq;
      lq.z += xv[c].z * wq; lq.w += xv[c].w * wq;
    }
    const float4 ek = make_float4(__expf(lk.x), __expf(lk.y),
                                  __expf(lk.z), __expf(lk.w));
    const float4 eq = make_float4(__expf(lq.x), __expf(lq.y),
                                  __expf(lq.z), __expf(lq.w));
    const float sK = waveSumRow3((ek.x + ek.y) + (ek.z + ek.w));
    const float sQ = waveSumRow3((eq.x + eq.y) + (eq.z + eq.w));
    o3 += (p == 0) ? sK : ((p == 1) ? sQ : 0.f);
#pragma unroll
    for (int c = 0; c < CPH; ++c) {
      float dk = (xv[c].x * ek.x + xv[c].y * ek.y) + (xv[c].z * ek.z + xv[c].w * ek.w);
      float dq = (xv[c].x * eq.x + xv[c].y * eq.y) + (xv[c].z * eq.z + xv[c].w * eq.w);
      float cs = (xv[c].x + xv[c].y) + (xv[c].z + xv[c].w);
      dk = waveSumRow3(dk);
      dq = waveSumRow3(dq);
      cs = waveSumRow3(cs);
      if (p == c) { o0 += dk; o1 += dq; o2 += cs; }
    }
  }
  // record (comp-major: [dk16][dq16][cs16][s16]) — row 3 lanes hold totals
  float* rec = prec + ((long)head * 32 + jg * 4 + wid) * 64;
  if ((lane >> 4) == 3) {
    rec[p] = o0; rec[16 + p] = o1; rec[32 + p] = o2; rec[48 + p] = o3;
  }
  __syncthreads();
  __threadfence();
  if (t == 0)
    __hip_atomic_fetch_add(&cnt[head], 1, __ATOMIC_RELEASE,
                           __HIP_MEMORY_SCOPE_AGENT);
  // spin: 1 lane per wave, relaxed agent loads (coherent point, no L2 inv)
  if (lane == 0) {
    while (__hip_atomic_load(&cnt[head], __ATOMIC_RELAXED,
                             __HIP_MEMORY_SCOPE_AGENT) < JG)
      __builtin_amdgcn_s_sleep(8);
  }
  __syncthreads();
  // one acquire per thread: orders + invalidates for the record reads below
  (void)__hip_atomic_load(&cnt[head], __ATOMIC_ACQUIRE,
                          __HIP_MEMORY_SCOPE_AGENT);

  // ---- head finalize (all blocks redundantly; tiny) ----
  const float* recs = prec + (long)head * 32 * 64;
  float v = 0.f;
#pragma unroll 8
  for (int r = 0; r < 32; ++r) v += recs[r * 64 + lane];

  __shared__ float slotS[64], muS[CPH], h1S[8], KvS[CPH], QvS[CPH],
      scS[CPH], ofS[CPH];
  if (wid == 0) slotS[lane] = v;
  __syncthreads();
  if (t < CPH) {
    const float sk = slotS[48], sq = slotS[49];
    const float mu = slotS[32 + t] * (1.f / N);
    muS[t] = mu;
    KvS[t] = slotS[t] / sk - mu;
    QvS[t] = slotS[16 + t] / sq - mu;
  }
  __syncthreads();
  if (t < 8) {
    float a = pb1[h * 8 + t];
#pragma unroll
    for (int i = 0; i < 16; ++i) a += muS[i] * pw1[(h * 8 + t) * 16 + i];
    h1S[t] = fmaxf(a, 0.f);
  }
  __syncthreads();
  if (t < CPH) {
    float a = pb2[h * 16 + t];
#pragma unroll
    for (int k = 0; k < 8; ++k) a += h1S[k] * pw2[(h * 16 + t) * 8 + k];
    const float P = 1.f / (1.f + __expf(-a));
    scS[t] = P;
    ofS[t] = (KvS[t] - QvS[t]) * P;
  }
  __syncthreads();
  if (jg == 0 && t == 0) {
    float sdp = 0.f;
#pragma unroll
    for (int c2 = 0; c2 < CPH; ++c2) sdp += KvS[c2] * QvS[c2];
    atomicAdd(&dp[b], sdp * (1.f / C));
  }

  // ---- phase 2: y = x*scale + offset over the SAME chunks, reverse order ----
  float* yh = y + ((long)(b * C + h * CPH)) * N;
  for (int s = CPB - 1; s >= 0; --s) {
    const long off = (long)(jg * CPB + s) * 1024 + t * 4;
    float4 xv[CPH];
#pragma unroll
    for (int c = 0; c < CPH; ++c) xv[c] = *(const float4*)(xh + off + (long)c * N);
#pragma unroll
    for (int c = 0; c < CPH; ++c) {
      const float sc = scS[c], of = ofS[c];
      f4v w;
      w.x = xv[c].x * sc + of; w.y = xv[c].y * sc + of;
      w.z = xv[c].z * sc + of; w.w = xv[c].w * sc + of;
      __builtin_nontemporal_store(w, (f4v*)(yh + off + (long)c * N));
    }
  }
}

// ===========================================================================
// Fallback path: R9's proven 3-kernel pipeline (used if cooperative launch
// is unavailable or ws too small).
__global__ __launch_bounds__(256, 4) void kA(const float* __restrict__ x,
                                             const float* __restrict__ kw,
                                             const float* __restrict__ qw,
                                             float* __restrict__ prec) {
  const int b = blockIdx.z, h = blockIdx.y, j = blockIdx.x;
  const int t = threadIdx.x, lane = t & 63, wid = t >> 6;
  const int p = lane & 15;
  const float* xs = x + ((long)(b * C + h * CPH)) * N + (long)j * 1024 + t * 4;
  float4 xv[CPH];
#pragma unroll
  for (int c = 0; c < CPH; ++c) xv[c] = *(const float4*)(xs + (long)c * N);
  float4 lk = make_float4(0.f, 0.f, 0.f, 0.f);
  float4 lq = make_float4(0.f, 0.f, 0.f, 0.f);
#pragma unroll
  for (int c = 0; c < CPH; ++c) {
    const float wkc = kw[h * CPH + c], wqc = qw[h * CPH + c];
    lk.x += xv[c].x * wkc; lk.y += xv[c].y * wkc;
    lk.z += xv[c].z * wkc; lk.w += xv[c].w * wkc;
    lq.x += xv[c].x * wqc; lq.y += xv[c].y * wqc;
    lq.z += xv[c].z * wqc; lq.w += xv[c].w * wqc;
  }
  const float4 ek = make_float4(__expf(lk.x), __expf(lk.y),
                                __expf(lk.z), __expf(lk.w));
  const float4 eq = make_float4(__expf(lq.x), __expf(lq.y),
                                __expf(lq.z), __expf(lq.w));
  const float sK = waveSumRow3((ek.x + ek.y) + (ek.z + ek.w));
  const float sQ = waveSumRow3((eq.x + eq.y) + (eq.z + eq.w));
  float o0 = 0.f, o1 = 0.f, o2 = 0.f;
#pragma unroll
  for (int c = 0; c < CPH; ++c) {
    float dk = (xv[c].x * ek.x + xv[c].y * ek.y) + (xv[c].z * ek.z + xv[c].w * ek.w);
    float dq = (xv[c].x * eq.x + xv[c].y * eq.y) + (xv[c].z * eq.z + xv[c].w * eq.w);
    float cs = (xv[c].x + xv[c].y) + (xv[c].z + xv[c].w);
    dk = waveSumRow3(dk); dq = waveSumRow3(dq); cs = waveSumRow3(cs);
    if (p == c) { o0 = dk; o1 = dq; o2 = cs; }
  }
  const float o3 = (p == 0) ? sK : ((p == 1) ? sQ : 0.f);
  if ((lane >> 4) == 3) {
    const long ridx = (((long)(b * NH + h)) * NJ + j) * 4 + wid;
    f4v r; r.x = o0; r.y = o1; r.z = o2; r.w = o3;
    *(f4v*)(prec + ridx * 64 + p * 4) = r;
  }
}

__global__ __launch_bounds__(512) void k4(const float* __restrict__ prec,
                                          const float* __restrict__ pw1,
                                          const float* __restrict__ pb1,
                                          const float* __restrict__ pw2,
                                          const float* __restrict__ pb2,
                                          float* __restrict__ scale,
                                          float* __restrict__ offset,
                                          float* __restrict__ dpOut) {
  const int b = blockIdx.x;
  const int c = threadIdx.x;
  const int h = c >> 4, i = c & 15;
  const float4* rec4 = (const float4*)prec + ((long)(b * NH + h)) * NREC * 16;
  float dk = 0.f, dq = 0.f, cs = 0.f, sacc = 0.f;
  for (int j = 0; j < NREC; ++j) {
    const float4 r = rec4[j * 16 + i];
    dk += r.x; dq += r.y; cs += r.z; sacc += r.w;
  }
  __shared__ float skS[NH], sqS[NH];
  if (i == 0) skS[h] = sacc;
  if (i == 1) sqS[h] = sacc;
  __syncthreads();
  const float sk = skS[h], sq = sqS[h];
  const float mu = cs * (1.f / N);
  const float Kv = dk / sk - mu;
  const float Qv = dq / sq - mu;
  __shared__ float muS[C], h1S[256];
  muS[c] = mu;
  __syncthreads();
  if (c < 256) {
    const int g = c >> 3;
    float a = pb1[c];
#pragma unroll
    for (int k = 0; k < 16; ++k) a += muS[g * 16 + k] * pw1[c * 16 + k];
    h1S[c] = fmaxf(a, 0.f);
  }
  __syncthreads();
  float a = pb2[c];
  const int g2 = c >> 4;
#pragma unroll
  for (int k = 0; k < 8; ++k) a += h1S[g2 * 8 + k] * pw2[c * 8 + k];
  const float P = 1.f / (1.f + __expf(-a));
  scale[b * C + c] = P;
  offset[b * C + c] = (Kv - Qv) * P;
  float pdp = wrs(Kv * Qv);
  __shared__ float pS[8];
  const int lane = c & 63, wid = c >> 6;
  if (lane == 0) pS[wid] = pdp;
  __syncthreads();
  if (c == 0) {
    float tot = 0.f;
    for (int w = 0; w < 8; ++w) tot += pS[w];
    dpOut[b] = tot * (1.f / C);
  }
}

__global__ __launch_bounds__(256) void k5(const float* __restrict__ x,
                                          const float* __restrict__ scale,
                                          const float* __restrict__ offset,
                                          float* __restrict__ y) {
  const int b = blockIdx.z, cc = blockIdx.y;
  const int t = threadIdx.x;
  const long base = ((long)(b * C + cc)) * N + (long)blockIdx.x * 4096;
  const float s = scale[b * C + cc], o = offset[b * C + cc];
#pragma unroll
  for (int k = 0; k < 4; ++k) {
    const long i = base + (long)(k * 256 + t) * 4;
    const float4 v = *(const float4*)(x + i);
    f4v w;
    w.x = v.x * s + o; w.y = v.y * s + o;
    w.z = v.z * s + o; w.w = v.w * s + o;
    __builtin_nontemporal_store(w, (f4v*)(y + i));
  }
}

} // namespace

extern "C" void kernel_launch(void* const* d_in, const int* in_sizes, int n_in,
                              void* d_out, int out_size, void* d_ws, size_t ws_size,
                              hipStream_t stream) {
  const float* x   = (const float*)d_in[0];
  const float* pw1 = (const float*)d_in[1];
  const float* pb1 = (const float*)d_in[2];
  const float* pw2 = (const float*)d_in[3];
  const float* pb2 = (const float*)d_in[4];
  const float* kw  = (const float*)d_in[5];
  // d_in[6]=kb, d_in[8]=qb unused: biases cancel in softmax (shift-invariant);
  // sum_n attn = 1 folds mean-subtraction into the finalize.
  const float* qw  = (const float*)d_in[7];
  float* out = (float*)d_out;
  float* ws  = (float*)d_ws;

  // fused-path workspace: 128 int counters + 1 MB records
  constexpr long FPREC = (long)B * NH * 32 * 64;  // 262144 floats
  const bool wsOK = ws_size >= (size_t)(4096 + FPREC) * sizeof(float);

  bool launched = false;
  if (wsOK) {
    int* cnt = (int*)ws;
    float* prec = ws + 4096;
    float* dpp = out + YSIZE;
    float* yp = out;
    hipMemsetAsync(ws, 0, B * NH * sizeof(int), stream);
    hipMemsetAsync(dpp, 0, B * sizeof(float), stream);
    void* args[] = {(void*)&x,   (void*)&kw,  (void*)&qw,  (void*)&pw1,
                    (void*)&pb1, (void*)&pw2, (void*)&pb2, (void*)&prec,
                    (void*)&cnt, (void*)&dpp, (void*)&yp};
    const hipError_t e = hipLaunchCooperativeKernel(
        (const void*)fused, dim3(JG, NH, B), dim3(256), args, 0, stream);
    launched = (e == hipSuccess);
  }

  if (!launched) {
    // R9 fallback (3 kernels)
    float* scale  = ws;
    float* offset = ws + 2048;
    constexpr long PREC = (long)B * NH * NREC * 64;  // 4 MB records
    float* prec = (ws_size >= (size_t)(4096 + PREC) * sizeof(float))
                      ? (ws + 4096) : out;
    hipLaunchKernelGGL(kA, dim3(NJ, NH, B), dim3(256), 0, stream,
                       x, kw, qw, prec);
    hipLaunchKernelGGL(k4, dim3(B), dim3(C), 0, stream,
                       prec, pw1, pb1, pw2, pb2, scale, offset, out + YSIZE);
    hipLaunchKernelGGL(k5, dim3(N / 4096, C, B), dim3(256), 0, stream,
                       x, scale, offset, out);
  }
}

// Round 12
// 143.941 us; speedup vs baseline: 2.7387x; 2.7387x over previous
//
#include <hip/hip_runtime.h>
#include <math.h>

namespace {

constexpr int B = 4;
constexpr int C = 512;
constexpr int NH = 32;          // heads
constexpr int CPH = 16;         // channels per head
constexpr int N = 32 * 32 * 32; // 32768 spatial
constexpr int NJ = 32;          // chunks (1024 n) per head
constexpr int NREC = NJ * 4;    // wave-records per head (32 blocks x 4 waves)
constexpr long YSIZE = (long)B * C * N;  // 67,108,864

typedef float f4v __attribute__((ext_vector_type(4)));

__device__ inline float wrs(float v) {
#pragma unroll
  for (int o = 32; o > 0; o >>= 1) v += __shfl_xor(v, o);
  return v;
}

// DPP add, compile-time control + row mask (disabled rows: old=0 added).
template <int CTRL, int RM = 0xF>
__device__ __forceinline__ float dppAdd(float v) {
  const int r = __builtin_amdgcn_update_dpp(
      0, __float_as_int(v), CTRL, RM, 0xF, true);
  return v + __int_as_float(r);
}
// Full 64-lane sum on the VALU pipe only; total valid in row 3 (lanes 48-63).
__device__ __forceinline__ float waveSumRow3(float v) {
  v = dppAdd<0xB1>(v);          // + lane^1
  v = dppAdd<0x4E>(v);          // + lane^2
  v = dppAdd<0x124>(v);         // row_ror:4
  v = dppAdd<0x128>(v);         // row_ror:8 -> 16-lane row sum
  v = dppAdd<0x142, 0xA>(v);    // row_bcast15: rows 1,3 += rows 0,2
  v = dppAdd<0x143, 0xC>(v);    // row_bcast31: rows 2,3 += lower half
  return v;
}

// ---------------------------------------------------------------------------
// kA: single pass over x (R9-proven, unchanged). grid (32, NH, B), 256 thr.
// Block = 1024 consecutive n of one (b,h). 16 channel float4 loads batched
// into a register tile; logits (no max-shift: ~unit variance, fp32 exp safe
// to 88); exp; weighted sums; pure-VALU DPP wave reduction; row 3 stores one
// 256 B record/wave. Record layout is INTERLEAVED [p][4]: float4 at p*4 =
// {dk[p], dq[p], cs[p], s-slot(p==0:sK, p==1:sQ)} — k4 must read float4s.
// NORMAL (caching) loads on purpose: they populate L3 for k5's NT reads.
__global__ __launch_bounds__(256, 4) void kA(const float* __restrict__ x,
                                             const float* __restrict__ kw,
                                             const float* __restrict__ qw,
                                             float* __restrict__ prec) {
  const int b = blockIdx.z, h = blockIdx.y, j = blockIdx.x;
  const int t = threadIdx.x, lane = t & 63, wid = t >> 6;
  const int p = lane & 15;
  const float* xs = x + ((long)(b * C + h * CPH)) * N + (long)j * 1024 + t * 4;

  float4 xv[CPH];
#pragma unroll
  for (int c = 0; c < CPH; ++c) xv[c] = *(const float4*)(xs + (long)c * N);

  float4 lk = make_float4(0.f, 0.f, 0.f, 0.f);
  float4 lq = make_float4(0.f, 0.f, 0.f, 0.f);
#pragma unroll
  for (int c = 0; c < CPH; ++c) {
    const float wkc = kw[h * CPH + c], wqc = qw[h * CPH + c];
    lk.x += xv[c].x * wkc; lk.y += xv[c].y * wkc;
    lk.z += xv[c].z * wkc; lk.w += xv[c].w * wkc;
    lq.x += xv[c].x * wqc; lq.y += xv[c].y * wqc;
    lq.z += xv[c].z * wqc; lq.w += xv[c].w * wqc;
  }
  const float4 ek = make_float4(__expf(lk.x), __expf(lk.y),
                                __expf(lk.z), __expf(lk.w));
  const float4 eq = make_float4(__expf(lq.x), __expf(lq.y),
                                __expf(lq.z), __expf(lq.w));
  const float sK = waveSumRow3((ek.x + ek.y) + (ek.z + ek.w));
  const float sQ = waveSumRow3((eq.x + eq.y) + (eq.z + eq.w));

  float o0 = 0.f, o1 = 0.f, o2 = 0.f;
#pragma unroll
  for (int c = 0; c < CPH; ++c) {
    float dk = (xv[c].x * ek.x + xv[c].y * ek.y) + (xv[c].z * ek.z + xv[c].w * ek.w);
    float dq = (xv[c].x * eq.x + xv[c].y * eq.y) + (xv[c].z * eq.z + xv[c].w * eq.w);
    float cs = (xv[c].x + xv[c].y) + (xv[c].z + xv[c].w);
    dk = waveSumRow3(dk); dq = waveSumRow3(dq); cs = waveSumRow3(cs);
    if (p == c) { o0 = dk; o1 = dq; o2 = cs; }
  }
  const float o3 = (p == 0) ? sK : ((p == 1) ? sQ : 0.f);

  if ((lane >> 4) == 3) {  // row 3 holds the valid wave totals
    const long ridx = (((long)(b * NH + h)) * NJ + j) * 4 + wid;
    f4v r; r.x = o0; r.y = o1; r.z = o2; r.w = o3;
    *(f4v*)(prec + ridx * 64 + p * 4) = r;
  }
}

// ---------------------------------------------------------------------------
// k4: combine wave-records + finalize (R9-proven, unchanged). grid(B),
// 512 threads (thread = channel). Reads records as float4 per channel —
// matches kA's interleaved [p][4] layout.
__global__ __launch_bounds__(512) void k4(const float* __restrict__ prec,
                                          const float* __restrict__ pw1,
                                          const float* __restrict__ pb1,
                                          const float* __restrict__ pw2,
                                          const float* __restrict__ pb2,
                                          float* __restrict__ scale,
                                          float* __restrict__ offset,
                                          float* __restrict__ dpOut) {
  const int b = blockIdx.x;
  const int c = threadIdx.x;           // 0..511
  const int h = c >> 4, i = c & 15;
  const float4* rec4 = (const float4*)prec + ((long)(b * NH + h)) * NREC * 16;

  float dk = 0.f, dq = 0.f, cs = 0.f, sacc = 0.f;
  for (int j = 0; j < NREC; ++j) {
    const float4 r = rec4[j * 16 + i];
    dk += r.x; dq += r.y; cs += r.z; sacc += r.w;  // r.w: sK at i==0, sQ at i==1
  }
  __shared__ float skS[NH], sqS[NH];
  if (i == 0) skS[h] = sacc;
  if (i == 1) sqS[h] = sacc;
  __syncthreads();
  const float sk = skS[h], sq = sqS[h];

  const float mu = cs * (1.f / N);
  const float Kv = dk / sk - mu;
  const float Qv = dq / sq - mu;

  __shared__ float muS[C], h1S[256];
  muS[c] = mu;
  __syncthreads();
  if (c < 256) {
    const int g = c >> 3;
    float a = pb1[c];
#pragma unroll
    for (int k = 0; k < 16; ++k) a += muS[g * 16 + k] * pw1[c * 16 + k];
    h1S[c] = fmaxf(a, 0.f);
  }
  __syncthreads();
  float a = pb2[c];
  const int g2 = c >> 4;
#pragma unroll
  for (int k = 0; k < 8; ++k) a += h1S[g2 * 8 + k] * pw2[c * 8 + k];
  const float P = 1.f / (1.f + __expf(-a));
  scale[b * C + c] = P;
  offset[b * C + c] = (Kv - Qv) * P;

  float pdp = wrs(Kv * Qv);
  __shared__ float pS[8];
  const int lane = c & 63, wid = c >> 6;
  if (lane == 0) pS[wid] = pdp;
  __syncthreads();
  if (c == 0) {
    float tot = 0.f;
    for (int w = 0; w < 8; ++w) tot += pS[w];
    dpOut[b] = tot * (1.f / C);
  }
}

// ---------------------------------------------------------------------------
// k5: y = x * scale[b,c] + offset[b,c]. grid (N/4096, C, B), block 256.
// THE single experimental change vs R9: NONTEMPORAL loads. x is exactly
// L3-sized; allocating reads self-evict x's unread lines under LRU (k5
// measured at pure-HBM floor). No-allocate reads let L3 keep kA's
// insertions -> reads mostly hit L3; k5 becomes write-bound. NT stores
// (R7-proven) keep the y stream from evicting x.
__global__ __launch_bounds__(256) void k5(const float* __restrict__ x,
                                          const float* __restrict__ scale,
                                          const float* __restrict__ offset,
                                          float* __restrict__ y) {
  const int b = blockIdx.z, cc = blockIdx.y;
  const int t = threadIdx.x;
  const long base = ((long)(b * C + cc)) * N + (long)blockIdx.x * 4096;
  const float s = scale[b * C + cc], o = offset[b * C + cc];
#pragma unroll
  for (int k = 0; k < 4; ++k) {
    const long i = base + (long)(k * 256 + t) * 4;
    const f4v v = __builtin_nontemporal_load((const f4v*)(x + i));
    f4v w;
    w.x = v.x * s + o; w.y = v.y * s + o;
    w.z = v.z * s + o; w.w = v.w * s + o;
    __builtin_nontemporal_store(w, (f4v*)(y + i));
  }
}

} // namespace

extern "C" void kernel_launch(void* const* d_in, const int* in_sizes, int n_in,
                              void* d_out, int out_size, void* d_ws, size_t ws_size,
                              hipStream_t stream) {
  const float* x   = (const float*)d_in[0];
  const float* pw1 = (const float*)d_in[1];
  const float* pb1 = (const float*)d_in[2];
  const float* pw2 = (const float*)d_in[3];
  const float* pb2 = (const float*)d_in[4];
  const float* kw  = (const float*)d_in[5];
  // d_in[6]=kb, d_in[8]=qb unused: biases cancel in softmax (shift-invariant);
  // sum_n attn = 1 folds mean-subtraction into the finalize.
  const float* qw  = (const float*)d_in[7];
  float* out = (float*)d_out;
  float* ws  = (float*)d_ws;

  // scale/offset in ws (read by k5 while k5 writes out)
  float* scale  = ws;          // 2048
  float* offset = ws + 2048;   // 2048

  // wave-records: B*NH*NREC*64 = 1,048,576 floats (4 MB)
  constexpr long PREC = (long)B * NH * NREC * 64;
  float* prec;
  if (ws_size >= (size_t)(4096 + PREC) * sizeof(float)) {
    prec = ws + 4096;
  } else {
    prec = out;  // consumed by k4 before k5 overwrites out
  }

  hipLaunchKernelGGL(kA, dim3(NJ, NH, B), dim3(256), 0, stream,
                     x, kw, qw, prec);
  hipLaunchKernelGGL(k4, dim3(B), dim3(C), 0, stream,
                     prec, pw1, pb1, pw2, pb2, scale, offset, out + YSIZE);
  hipLaunchKernelGGL(k5, dim3(N / 4096, C, B), dim3(256), 0, stream,
                     x, scale, offset, out);
}